// Round 3
// baseline (245.791 us; speedup 1.0000x reference)
//
#include <hip/hip_runtime.h>
#include <hip/hip_bf16.h>

#define BB 4
#define SS 2048
#define DM 1024
#define DN 64

typedef short short8 __attribute__((ext_vector_type(8)));
typedef float f32x4 __attribute__((ext_vector_type(4)));
typedef unsigned short ushort;

__device__ __forceinline__ ushort f2bf(float f) {
    union { float f; unsigned u; } v; v.f = f;
    unsigned r = v.u + 0x7fffu + ((v.u >> 16) & 1u);
    return (ushort)(r >> 16);
}

__device__ __forceinline__ void gll16(const void* g, void* l) {
    __builtin_amdgcn_global_load_lds(
        (const __attribute__((address_space(1))) void*)g,
        (__attribute__((address_space(3))) void*)l, 16, 0, 0);
}

// ---------------------------------------------------------------------------
// prep_w: convert w_q|w_k|w_v (each [64][1024] fp32) to bf16, same layout.
// ---------------------------------------------------------------------------
__global__ __launch_bounds__(256) void prep_w(
    const float* __restrict__ wq, const float* __restrict__ wk,
    const float* __restrict__ wv, ushort* __restrict__ w_bf)
{
    int i = blockIdx.x * 256 + threadIdx.x;          // 49152 threads, 4 floats each
    int p = i >> 14;                                  // 16384 float4 per proj
    int j = (i & 16383) * 4;
    const float* src = (p == 0) ? wq : (p == 1) ? wk : wv;
    float4 f = *(const float4*)(src + j);
    ushort o[4] = { f2bf(f.x), f2bf(f.y), f2bf(f.z), f2bf(f.w) };
    *(unsigned long long*)(w_bf + p * 65536 + j) = *(unsigned long long*)o;
}

// ---------------------------------------------------------------------------
// proj: out = x @ w^T + b.
// R0-R2 lesson: 50-56us / ~1.05 TB/s invariant across occupancy 14->53% and
// coalesced reg-staging -> the limiter is in-flight BYTES (Little's law:
// need ~30-80 KB/CU outstanding vs loaded latency; reg staging + the
// __syncthreads vmcnt(0) drain collapse it to ~KB).
// v3: async global_load_lds width-16 for A (no VGPR dests), BARRIER-FREE
// (block = 1 wave = 16 rows; wave stages + consumes only its own rows),
// double-buffered with counted s_waitcnt vmcnt(16) - never 0 in the loop -
// so 16KB/wave stays in flight across compute. 32KB LDS/block -> 5 blocks/
// CU -> up to 80KB in flight per CU. LDS dest linear, global source XOR-
// pre-swizzled (16B granule) so A-frag ds_read_b128 is 2-way (free) not
// 16-way. W stays direct-from-global (L2-hot) - unchanged, isolates the
// A-path change.  qp/kp row-major bf16 [8192][64]; vpT [4][64][2048].
// ---------------------------------------------------------------------------
__global__ __launch_bounds__(64) void proj_kernel(
    const float* __restrict__ q, const float* __restrict__ k, const float* __restrict__ v,
    const ushort* __restrict__ w_bf,
    const float* __restrict__ bq, const float* __restrict__ bk, const float* __restrict__ bvp,
    ushort* __restrict__ qp, ushort* __restrict__ kp, ushort* __restrict__ vpT)
{
    __shared__ __align__(16) float sA[2][16][256];   // 32 KB: dbuf x 16 rows x 1KB

    const int lane = threadIdx.x;                    // one wave per block
    const int l16  = lane & 15;
    const int quad = lane >> 4;
    const int proj = blockIdx.y;
    const int m0   = blockIdx.x * 16;                // 512 row-groups per proj

    const float* x   = (proj == 0) ? q  : (proj == 1) ? k  : v;
    const ushort* wb = w_bf + proj * 65536;

    const int swz  = lane * 16;                      // staging byte offset in row
    const int swzr = (l16 & 7) << 4;                 // read-side XOR (same involution)

    f32x4 acc[4];
#pragma unroll
    for (int t = 0; t < 4; t++) acc[t] = (f32x4){0.f, 0.f, 0.f, 0.f};

    // stage chunk c_ (256 k-floats) into buffer b_: 16 x 1KB rows, one
    // wave-instr per row. LDS dest linear (uniform base + lane*16), global
    // source pre-swizzled by ((row&7)<<4) so reads can de-conflict.
#define STAGE(c_, b_)                                                         \
    {                                                                         \
        const char* gx = (const char*)x + (size_t)m0 * 4096 + (size_t)(c_) * 1024; \
        _Pragma("unroll")                                                     \
        for (int j = 0; j < 16; j++)                                          \
            gll16(gx + (size_t)j * 4096 + (swz ^ ((j & 7) << 4)),             \
                  &sA[b_][j][0]);                                             \
    }

    STAGE(0, 0);

#pragma unroll
    for (int c = 0; c < 4; c++) {
        const int cur = c & 1;
        if (c < 3) STAGE(c + 1, cur ^ 1);            // keep 16KB in flight
        __builtin_amdgcn_sched_barrier(0);
        if (c < 3) { asm volatile("s_waitcnt vmcnt(16)" ::: "memory"); }
        else       { asm volatile("s_waitcnt vmcnt(0)"  ::: "memory"); }
        __builtin_amdgcn_sched_barrier(0);

        // compute chunk c: rows m0..m0+15, K-slice [c*256, c*256+256)
#pragma unroll
        for (int s = 0; s < 8; s++) {
            const char* rb = (const char*)&sA[cur][l16][0];
            const int o = s * 128 + quad * 32;
            f32x4 fa0 = *(const f32x4*)(rb + ((o)      ^ swzr));
            f32x4 fa1 = *(const f32x4*)(rb + ((o + 16) ^ swzr));
            ushort ta[8] = { f2bf(fa0[0]), f2bf(fa0[1]), f2bf(fa0[2]), f2bf(fa0[3]),
                             f2bf(fa1[0]), f2bf(fa1[1]), f2bf(fa1[2]), f2bf(fa1[3]) };
            short8 a = *(short8*)ta;
            const int kglob = c * 256 + s * 32;
#pragma unroll
            for (int t = 0; t < 4; t++) {
                short8 b = *(const short8*)(wb + (size_t)(t * 16 + l16) * DM
                                               + kglob + quad * 8);
                acc[t] = __builtin_amdgcn_mfma_f32_16x16x32_bf16(a, b, acc[t], 0, 0, 0);
            }
        }
    }
#undef STAGE

    // epilogue: C/D layout: n = t*16 + l16, row = quad*4 + r
    const float* bias = (proj == 0) ? bq : (proj == 1) ? bk : bvp;
#pragma unroll
    for (int t = 0; t < 4; t++) {
        int n = t * 16 + l16;
        float bb_ = bias[n];
#pragma unroll
        for (int r = 0; r < 4; r++) {
            int grow = m0 + quad * 4 + r;
            ushort h = f2bf(acc[t][r] + bb_);
            if (proj == 0)      qp[(size_t)grow * DN + n] = h;
            else if (proj == 1) kp[(size_t)grow * DN + n] = h;
            else {
                int bb = grow >> 11, s = grow & 2047;
                vpT[((size_t)bb * DN + n) * SS + s] = h;
            }
        }
    }
}

// ---------------------------------------------------------------------------
// flash: barrier-free. One wave = 16 q rows x one key-slice. All MFMA frags
// loaded directly from global (bf16, 16B/lane). P roundtrip via wave-private
// LDS. Mask applied in fp32. Writes unnormalized partial (O, m, l).
// ---------------------------------------------------------------------------
__global__ __launch_bounds__(256, 4) void flash_kernel(
    const float* __restrict__ mask,
    const ushort* __restrict__ qp,
    const ushort* __restrict__ kp,
    const ushort* __restrict__ vpT,
    float* __restrict__ part_O,     // [split][8192][64]
    float* __restrict__ part_ml,    // [split][8192][2]
    int nslice, int keys_per_slice)
{
    __shared__ __align__(16) ushort p_lds[4][16][80];  // 160B row stride: quads spread 8 banks

    const int tid  = threadIdx.x;
    const int wv   = tid >> 6;
    const int lane = tid & 63;
    const int l16  = lane & 15;
    const int quad = lane >> 4;

    const int gw     = blockIdx.x * 4 + wv;       // global wave id
    const int qg     = gw & 127;                  // q-group within batch (128/batch)
    const int rest   = gw >> 7;
    const int slice  = rest % nslice;
    const int b      = rest / nslice;

    // Q fragments (A-layout), direct from global
    const ushort* qbase = qp + ((size_t)b * SS + qg * 16 + l16) * DN + quad * 8;
    short8 aq0 = *(const short8*)(qbase);
    short8 aq1 = *(const short8*)(qbase + 32);

    float m_r[4] = { -__builtin_inff(), -__builtin_inff(),
                     -__builtin_inff(), -__builtin_inff() };
    float l_r[4] = { 0.f, 0.f, 0.f, 0.f };
    f32x4 Oacc[4];
#pragma unroll
    for (int t = 0; t < 4; t++) Oacc[t] = (f32x4){0.f, 0.f, 0.f, 0.f};

    const size_t mrow0 = ((size_t)b * SS + qg * 16 + quad * 4) * SS;
    const int k_begin = slice * keys_per_slice;
    const int k_end   = k_begin + keys_per_slice;

    for (int k0 = k_begin; k0 < k_end; k0 += 64) {
        // fp32 mask loads (argmax decided by ~1e2 score gaps -> must stay fp32)
        float mk[4][4];
#pragma unroll
        for (int t = 0; t < 4; t++)
#pragma unroll
            for (int r = 0; r < 4; r++)
                mk[t][r] = mask[mrow0 + (size_t)r * SS + k0 + t * 16 + l16];

        // S = qp . kp^T ; B-frags direct from global kp (row-major)
        f32x4 sc[4];
#pragma unroll
        for (int t = 0; t < 4; t++) {
            const ushort* kb_ = kp + ((size_t)b * SS + k0 + t * 16 + l16) * DN + quad * 8;
            short8 bk0 = *(const short8*)(kb_);
            short8 bk1 = *(const short8*)(kb_ + 32);
            f32x4 z = (f32x4){0.f, 0.f, 0.f, 0.f};
            z = __builtin_amdgcn_mfma_f32_16x16x32_bf16(aq0, bk0, z, 0, 0, 0);
            z = __builtin_amdgcn_mfma_f32_16x16x32_bf16(aq1, bk1, z, 0, 0, 0);
            sc[t] = z;
        }

        // online softmax per accumulator reg (one q row per reg)
#pragma unroll
        for (int r = 0; r < 4; r++) {
            float s[4];
            float tmax = -__builtin_inff();
#pragma unroll
            for (int t = 0; t < 4; t++) {
                s[t] = sc[t][r] * 0.125f - 1e9f * mk[t][r];
                tmax = fmaxf(tmax, s[t]);
            }
#pragma unroll
            for (int off = 8; off >= 1; off >>= 1)
                tmax = fmaxf(tmax, __shfl_xor(tmax, off, 16));
            float mnew  = fmaxf(m_r[r], tmax);
            float alpha = __expf(m_r[r] - mnew);
            m_r[r] = mnew;
            float rs = 0.f;
#pragma unroll
            for (int t = 0; t < 4; t++) {
                float pv = __expf(s[t] - mnew);
                rs += pv;
                p_lds[wv][quad * 4 + r][t * 16 + l16] = f2bf(pv);
            }
#pragma unroll
            for (int off = 8; off >= 1; off >>= 1)
                rs += __shfl_xor(rs, off, 16);
            l_r[r] = l_r[r] * alpha + rs;
#pragma unroll
            for (int tf = 0; tf < 4; tf++)
                Oacc[tf][r] *= alpha;
        }
        // wave-private LDS roundtrip: in-order DS pipe, no barrier needed

        short8 ap0 = *(const short8*)&p_lds[wv][l16][quad * 8];
        short8 ap1 = *(const short8*)&p_lds[wv][l16][32 + quad * 8];
#pragma unroll
        for (int tf = 0; tf < 4; tf++) {
            const ushort* vb_ = vpT + ((size_t)b * DN + tf * 16 + l16) * SS + k0 + quad * 8;
            short8 bv0 = *(const short8*)(vb_);
            short8 bv1 = *(const short8*)(vb_ + 32);
            Oacc[tf] = __builtin_amdgcn_mfma_f32_16x16x32_bf16(ap0, bv0, Oacc[tf], 0, 0, 0);
            Oacc[tf] = __builtin_amdgcn_mfma_f32_16x16x32_bf16(ap1, bv1, Oacc[tf], 0, 0, 0);
        }
    }

    // store partials (unnormalized O, plus m and l)
    const int rowg = (b * SS + qg * 16) + quad * 4;   // global row base for this quad
#pragma unroll
    for (int r = 0; r < 4; r++) {
        size_t row = (size_t)rowg + r;
        if (l16 == 0) {
            part_ml[((size_t)slice * (BB * SS) + row) * 2 + 0] = m_r[r];
            part_ml[((size_t)slice * (BB * SS) + row) * 2 + 1] = l_r[r];
        }
#pragma unroll
        for (int tf = 0; tf < 4; tf++)
            part_O[((size_t)slice * (BB * SS) + row) * DN + tf * 16 + l16] = Oacc[tf][r];
    }
}

// ---------------------------------------------------------------------------
// combine: merge nslice partials per row; normalize.
// ---------------------------------------------------------------------------
__global__ __launch_bounds__(256) void combine_kernel(
    const float* __restrict__ part_O, const float* __restrict__ part_ml,
    float* __restrict__ out, int nslice)
{
    const int tid = threadIdx.x;
    const int row = blockIdx.x * 4 + (tid >> 6);
    const int f   = tid & 63;

    float ms[8], ls[8];
    float M = -__builtin_inff();
    for (int i = 0; i < nslice; i++) {
        ms[i] = part_ml[((size_t)i * (BB * SS) + row) * 2 + 0];
        ls[i] = part_ml[((size_t)i * (BB * SS) + row) * 2 + 1];
        M = fmaxf(M, ms[i]);
    }
    float L = 0.f, acc = 0.f;
    for (int i = 0; i < nslice; i++) {
        float e = __expf(ms[i] - M);
        L += e * ls[i];
        acc += e * part_O[((size_t)i * (BB * SS) + row) * DN + f];
    }
    out[(size_t)row * DN + f] = acc / L;
}

extern "C" void kernel_launch(void* const* d_in, const int* in_sizes, int n_in,
                              void* d_out, int out_size, void* d_ws, size_t ws_size,
                              hipStream_t stream) {
    const float* q    = (const float*)d_in[0];
    const float* k    = (const float*)d_in[1];
    const float* v    = (const float*)d_in[2];
    const float* mask = (const float*)d_in[3];
    const float* wq   = (const float*)d_in[4];
    const float* bq   = (const float*)d_in[5];
    const float* wk   = (const float*)d_in[6];
    const float* bk   = (const float*)d_in[7];
    const float* wv   = (const float*)d_in[8];
    const float* bv   = (const float*)d_in[9];
    float* out = (float*)d_out;

    // workspace layout
    char* p = (char*)d_ws;
    ushort* w_bf = (ushort*)p;                 p += 3 * 65536 * sizeof(ushort);   // 384 KB
    ushort* qp   = (ushort*)p;                 p += (size_t)BB * SS * DN * 2;     // 1 MB
    ushort* kp   = (ushort*)p;                 p += (size_t)BB * SS * DN * 2;     // 1 MB
    ushort* vpT  = (ushort*)p;                 p += (size_t)BB * SS * DN * 2;     // 1 MB
    size_t fixed = (size_t)(p - (char*)d_ws);

    int split = 8;
    while (split > 1 &&
           fixed + (size_t)split * ((size_t)BB * SS * 2 * 4 + (size_t)BB * SS * DN * 4) > ws_size)
        split >>= 1;

    float* part_ml = (float*)p;                p += (size_t)split * BB * SS * 2 * 4;
    float* part_O  = (float*)p;

    int keys_per_slice = SS / split;

    prep_w<<<192, 256, 0, stream>>>(wq, wk, wv, w_bf);
    proj_kernel<<<dim3(512, 3), 64, 0, stream>>>(q, k, v, w_bf, bq, bk, bv, qp, kp, vpT);
    flash_kernel<<<128 * split, 256, 0, stream>>>(mask, qp, kp, vpT, part_O, part_ml,
                                                  split, keys_per_slice);
    combine_kernel<<<(BB * SS) / 4, 256, 0, stream>>>(part_O, part_ml, out, split);
}

// Round 4
// 230.681 us; speedup vs baseline: 1.0655x; 1.0655x over previous
//
#include <hip/hip_runtime.h>
#include <hip/hip_bf16.h>

#define BB 4
#define SS 2048
#define DM 1024
#define DN 64

typedef short short8 __attribute__((ext_vector_type(8)));
typedef float f32x4 __attribute__((ext_vector_type(4)));
typedef unsigned short ushort;

__device__ __forceinline__ ushort f2bf(float f) {
    union { float f; unsigned u; } v; v.f = f;
    unsigned r = v.u + 0x7fffu + ((v.u >> 16) & 1u);
    return (ushort)(r >> 16);
}

// ---------------------------------------------------------------------------
// prep_w: convert w_q|w_k|w_v (each [64][1024] fp32) to bf16, same layout.
// ---------------------------------------------------------------------------
__global__ __launch_bounds__(256) void prep_w(
    const float* __restrict__ wq, const float* __restrict__ wk,
    const float* __restrict__ wv, ushort* __restrict__ w_bf)
{
    int i = blockIdx.x * 256 + threadIdx.x;          // 49152 threads, 4 floats each
    int p = i >> 14;                                  // 16384 float4 per proj
    int j = (i & 16383) * 4;
    const float* src = (p == 0) ? wq : (p == 1) ? wk : wv;
    float4 f = *(const float4*)(src + j);
    ushort o[4] = { f2bf(f.x), f2bf(f.y), f2bf(f.z), f2bf(f.w) };
    *(unsigned long long*)(w_bf + p * 65536 + j) = *(unsigned long long*)o;
}

// ---------------------------------------------------------------------------
// proj: out = x @ w^T + b. ROUND-0 STRUCTURE (best measured: 49.6us median).
// R1 (occupancy 53%), R2 (coalesced LDS staging), R3 (async global_load_lds,
// counted vmcnt, 40KB/CU in flight) ALL failed to beat it -> regime is
// fixed-latency dominated; only per-wave dependent-chain ILP + total bytes
// matter. Single delta vs R0: K-loop unroll 2 -> 4 (doubles independent
// loads in flight inside the chain).
// Barrier-free: A-frags direct from global fp32, B-frags direct from bf16 w
// (L2-hot). One wave = 16 output rows, full K.
// qp/kp row-major bf16 [8192][64]; vp transposed [4][64][2048].
// ---------------------------------------------------------------------------
__global__ __launch_bounds__(128) void proj_kernel(
    const float* __restrict__ q, const float* __restrict__ k, const float* __restrict__ v,
    const ushort* __restrict__ w_bf,
    const float* __restrict__ bq, const float* __restrict__ bk, const float* __restrict__ bvp,
    ushort* __restrict__ qp, ushort* __restrict__ kp, ushort* __restrict__ vpT)
{
    const int tid  = threadIdx.x;
    const int proj = blockIdx.y;
    const int wv_id = tid >> 6;
    const int lane  = tid & 63;
    const int l16   = lane & 15;
    const int quad  = lane >> 4;
    const int g     = blockIdx.x * 2 + wv_id;   // 0..511 row-group
    const int m0    = g * 16;

    const float* x     = (proj == 0) ? q  : (proj == 1) ? k  : v;
    const ushort* wb   = w_bf + proj * 65536;
    const float* bias  = (proj == 0) ? bq : (proj == 1) ? bk : bvp;

    const float* arow = x + (size_t)(m0 + l16) * DM + quad * 8;

    f32x4 acc[4];
#pragma unroll
    for (int t = 0; t < 4; t++) acc[t] = (f32x4){0.f, 0.f, 0.f, 0.f};

#pragma unroll 4
    for (int kb = 0; kb < DM; kb += 32) {
        float4 f0 = *(const float4*)(arow + kb);
        float4 f1 = *(const float4*)(arow + kb + 4);
        ushort ta[8] = { f2bf(f0.x), f2bf(f0.y), f2bf(f0.z), f2bf(f0.w),
                         f2bf(f1.x), f2bf(f1.y), f2bf(f1.z), f2bf(f1.w) };
        short8 a = *(short8*)ta;
#pragma unroll
        for (int t = 0; t < 4; t++) {
            short8 b = *(const short8*)(wb + (size_t)(t * 16 + l16) * DM + kb + quad * 8);
            acc[t] = __builtin_amdgcn_mfma_f32_16x16x32_bf16(a, b, acc[t], 0, 0, 0);
        }
    }

    // C/D layout: n = t*16 + l16, row = quad*4 + r
#pragma unroll
    for (int t = 0; t < 4; t++) {
        int n = t * 16 + l16;
        float bb_ = bias[n];
#pragma unroll
        for (int r = 0; r < 4; r++) {
            int grow = m0 + quad * 4 + r;
            ushort h = f2bf(acc[t][r] + bb_);
            if (proj == 0)      qp[(size_t)grow * DN + n] = h;
            else if (proj == 1) kp[(size_t)grow * DN + n] = h;
            else {
                int bb = grow >> 11, s = grow & 2047;
                vpT[((size_t)bb * DN + n) * SS + s] = h;
            }
        }
    }
}

// ---------------------------------------------------------------------------
// flash: barrier-free. One wave = 16 q rows x one key-slice. All MFMA frags
// loaded directly from global (bf16, 16B/lane). P roundtrip via wave-private
// LDS. Mask applied in fp32. Writes unnormalized partial (O, m, l).
// split=4 (was 8): halves part_O write+read traffic (~17 MB saved/iter);
// occupancy proven not to be the lever (R1).
// ---------------------------------------------------------------------------
__global__ __launch_bounds__(256, 4) void flash_kernel(
    const float* __restrict__ mask,
    const ushort* __restrict__ qp,
    const ushort* __restrict__ kp,
    const ushort* __restrict__ vpT,
    float* __restrict__ part_O,     // [split][8192][64]
    float* __restrict__ part_ml,    // [split][8192][2]
    int nslice, int keys_per_slice)
{
    __shared__ __align__(16) ushort p_lds[4][16][80];  // 160B row stride: quads spread 8 banks

    const int tid  = threadIdx.x;
    const int wv   = tid >> 6;
    const int lane = tid & 63;
    const int l16  = lane & 15;
    const int quad = lane >> 4;

    const int gw     = blockIdx.x * 4 + wv;       // global wave id
    const int qg     = gw & 127;                  // q-group within batch (128/batch)
    const int rest   = gw >> 7;
    const int slice  = rest % nslice;
    const int b      = rest / nslice;

    // Q fragments (A-layout), direct from global
    const ushort* qbase = qp + ((size_t)b * SS + qg * 16 + l16) * DN + quad * 8;
    short8 aq0 = *(const short8*)(qbase);
    short8 aq1 = *(const short8*)(qbase + 32);

    float m_r[4] = { -__builtin_inff(), -__builtin_inff(),
                     -__builtin_inff(), -__builtin_inff() };
    float l_r[4] = { 0.f, 0.f, 0.f, 0.f };
    f32x4 Oacc[4];
#pragma unroll
    for (int t = 0; t < 4; t++) Oacc[t] = (f32x4){0.f, 0.f, 0.f, 0.f};

    const size_t mrow0 = ((size_t)b * SS + qg * 16 + quad * 4) * SS;
    const int k_begin = slice * keys_per_slice;
    const int k_end   = k_begin + keys_per_slice;

    for (int k0 = k_begin; k0 < k_end; k0 += 64) {
        // fp32 mask loads (argmax decided by ~1e2 score gaps -> must stay fp32)
        float mk[4][4];
#pragma unroll
        for (int t = 0; t < 4; t++)
#pragma unroll
            for (int r = 0; r < 4; r++)
                mk[t][r] = mask[mrow0 + (size_t)r * SS + k0 + t * 16 + l16];

        // S = qp . kp^T ; B-frags direct from global kp (row-major)
        f32x4 sc[4];
#pragma unroll
        for (int t = 0; t < 4; t++) {
            const ushort* kb_ = kp + ((size_t)b * SS + k0 + t * 16 + l16) * DN + quad * 8;
            short8 bk0 = *(const short8*)(kb_);
            short8 bk1 = *(const short8*)(kb_ + 32);
            f32x4 z = (f32x4){0.f, 0.f, 0.f, 0.f};
            z = __builtin_amdgcn_mfma_f32_16x16x32_bf16(aq0, bk0, z, 0, 0, 0);
            z = __builtin_amdgcn_mfma_f32_16x16x32_bf16(aq1, bk1, z, 0, 0, 0);
            sc[t] = z;
        }

        // online softmax per accumulator reg (one q row per reg)
#pragma unroll
        for (int r = 0; r < 4; r++) {
            float s[4];
            float tmax = -__builtin_inff();
#pragma unroll
            for (int t = 0; t < 4; t++) {
                s[t] = sc[t][r] * 0.125f - 1e9f * mk[t][r];
                tmax = fmaxf(tmax, s[t]);
            }
#pragma unroll
            for (int off = 8; off >= 1; off >>= 1)
                tmax = fmaxf(tmax, __shfl_xor(tmax, off, 16));
            float mnew  = fmaxf(m_r[r], tmax);
            float alpha = __expf(m_r[r] - mnew);
            m_r[r] = mnew;
            float rs = 0.f;
#pragma unroll
            for (int t = 0; t < 4; t++) {
                float pv = __expf(s[t] - mnew);
                rs += pv;
                p_lds[wv][quad * 4 + r][t * 16 + l16] = f2bf(pv);
            }
#pragma unroll
            for (int off = 8; off >= 1; off >>= 1)
                rs += __shfl_xor(rs, off, 16);
            l_r[r] = l_r[r] * alpha + rs;
#pragma unroll
            for (int tf = 0; tf < 4; tf++)
                Oacc[tf][r] *= alpha;
        }
        // wave-private LDS roundtrip: in-order DS pipe, no barrier needed

        short8 ap0 = *(const short8*)&p_lds[wv][l16][quad * 8];
        short8 ap1 = *(const short8*)&p_lds[wv][l16][32 + quad * 8];
#pragma unroll
        for (int tf = 0; tf < 4; tf++) {
            const ushort* vb_ = vpT + ((size_t)b * DN + tf * 16 + l16) * SS + k0 + quad * 8;
            short8 bv0 = *(const short8*)(vb_);
            short8 bv1 = *(const short8*)(vb_ + 32);
            Oacc[tf] = __builtin_amdgcn_mfma_f32_16x16x32_bf16(ap0, bv0, Oacc[tf], 0, 0, 0);
            Oacc[tf] = __builtin_amdgcn_mfma_f32_16x16x32_bf16(ap1, bv1, Oacc[tf], 0, 0, 0);
        }
    }

    // store partials (unnormalized O, plus m and l)
    const int rowg = (b * SS + qg * 16) + quad * 4;   // global row base for this quad
#pragma unroll
    for (int r = 0; r < 4; r++) {
        size_t row = (size_t)rowg + r;
        if (l16 == 0) {
            part_ml[((size_t)slice * (BB * SS) + row) * 2 + 0] = m_r[r];
            part_ml[((size_t)slice * (BB * SS) + row) * 2 + 1] = l_r[r];
        }
#pragma unroll
        for (int tf = 0; tf < 4; tf++)
            part_O[((size_t)slice * (BB * SS) + row) * DN + tf * 16 + l16] = Oacc[tf][r];
    }
}

// ---------------------------------------------------------------------------
// combine: merge nslice partials per row; normalize.
// ---------------------------------------------------------------------------
__global__ __launch_bounds__(256) void combine_kernel(
    const float* __restrict__ part_O, const float* __restrict__ part_ml,
    float* __restrict__ out, int nslice)
{
    const int tid = threadIdx.x;
    const int row = blockIdx.x * 4 + (tid >> 6);
    const int f   = tid & 63;

    float ms[8], ls[8];
    float M = -__builtin_inff();
    for (int i = 0; i < nslice; i++) {
        ms[i] = part_ml[((size_t)i * (BB * SS) + row) * 2 + 0];
        ls[i] = part_ml[((size_t)i * (BB * SS) + row) * 2 + 1];
        M = fmaxf(M, ms[i]);
    }
    float L = 0.f, acc = 0.f;
    for (int i = 0; i < nslice; i++) {
        float e = __expf(ms[i] - M);
        L += e * ls[i];
        acc += e * part_O[((size_t)i * (BB * SS) + row) * DN + f];
    }
    out[(size_t)row * DN + f] = acc / L;
}

extern "C" void kernel_launch(void* const* d_in, const int* in_sizes, int n_in,
                              void* d_out, int out_size, void* d_ws, size_t ws_size,
                              hipStream_t stream) {
    const float* q    = (const float*)d_in[0];
    const float* k    = (const float*)d_in[1];
    const float* v    = (const float*)d_in[2];
    const float* mask = (const float*)d_in[3];
    const float* wq   = (const float*)d_in[4];
    const float* bq   = (const float*)d_in[5];
    const float* wk   = (const float*)d_in[6];
    const float* bk   = (const float*)d_in[7];
    const float* wv   = (const float*)d_in[8];
    const float* bv   = (const float*)d_in[9];
    float* out = (float*)d_out;

    // workspace layout
    char* p = (char*)d_ws;
    ushort* w_bf = (ushort*)p;                 p += 3 * 65536 * sizeof(ushort);   // 384 KB
    ushort* qp   = (ushort*)p;                 p += (size_t)BB * SS * DN * 2;     // 1 MB
    ushort* kp   = (ushort*)p;                 p += (size_t)BB * SS * DN * 2;     // 1 MB
    ushort* vpT  = (ushort*)p;                 p += (size_t)BB * SS * DN * 2;     // 1 MB
    size_t fixed = (size_t)(p - (char*)d_ws);

    int split = 4;
    while (split > 1 &&
           fixed + (size_t)split * ((size_t)BB * SS * 2 * 4 + (size_t)BB * SS * DN * 4) > ws_size)
        split >>= 1;

    float* part_ml = (float*)p;                p += (size_t)split * BB * SS * 2 * 4;
    float* part_O  = (float*)p;

    int keys_per_slice = SS / split;

    prep_w<<<192, 256, 0, stream>>>(wq, wk, wv, w_bf);
    proj_kernel<<<dim3(256, 3), 128, 0, stream>>>(q, k, v, w_bf, bq, bk, bv, qp, kp, vpT);
    flash_kernel<<<128 * split, 256, 0, stream>>>(mask, qp, kp, vpT, part_O, part_ml,
                                                  split, keys_per_slice);
    combine_kernel<<<(BB * SS) / 4, 256, 0, stream>>>(part_O, part_ml, out, split);
}

// Round 5
// 228.758 us; speedup vs baseline: 1.0745x; 1.0084x over previous
//
#include <hip/hip_runtime.h>
#include <hip/hip_bf16.h>

#define BB 4
#define SS 2048
#define DM 1024
#define DN 64

typedef short short8 __attribute__((ext_vector_type(8)));
typedef float f32x4 __attribute__((ext_vector_type(4)));
typedef unsigned short ushort;

__device__ __forceinline__ ushort f2bf(float f) {
    union { float f; unsigned u; } v; v.f = f;
    unsigned r = v.u + 0x7fffu + ((v.u >> 16) & 1u);
    return (ushort)(r >> 16);
}

// ---------------------------------------------------------------------------
// prep_w: convert w_q|w_k|w_v (each [64][1024] fp32) to bf16, same layout.
// ---------------------------------------------------------------------------
__global__ __launch_bounds__(256) void prep_w(
    const float* __restrict__ wq, const float* __restrict__ wk,
    const float* __restrict__ wv, ushort* __restrict__ w_bf)
{
    int i = blockIdx.x * 256 + threadIdx.x;          // 49152 threads, 4 floats each
    int p = i >> 14;                                  // 16384 float4 per proj
    int j = (i & 16383) * 4;
    const float* src = (p == 0) ? wq : (p == 1) ? wk : wv;
    float4 f = *(const float4*)(src + j);
    ushort o[4] = { f2bf(f.x), f2bf(f.y), f2bf(f.z), f2bf(f.w) };
    *(unsigned long long*)(w_bf + p * 65536 + j) = *(unsigned long long*)o;
}

// ---------------------------------------------------------------------------
// proj: out = x @ w^T + b. EXACT ROUND-0 STRUCTURE (best measured: 49.6us
// median). Falsified alternatives: occupancy x4 (R1), coalesced LDS staging
// (R2), async global_load_lds + counted vmcnt (R3), unroll 4 (R4). All
// neutral-to-worse -> fixed-latency regime; do not touch this kernel.
// Barrier-free: A-frags direct from global fp32, B-frags direct from bf16 w
// (L2-hot). One wave = 16 output rows, full K.
// qp/kp row-major bf16 [8192][64]; vp transposed [4][64][2048].
// ---------------------------------------------------------------------------
__global__ __launch_bounds__(128) void proj_kernel(
    const float* __restrict__ q, const float* __restrict__ k, const float* __restrict__ v,
    const ushort* __restrict__ w_bf,
    const float* __restrict__ bq, const float* __restrict__ bk, const float* __restrict__ bvp,
    ushort* __restrict__ qp, ushort* __restrict__ kp, ushort* __restrict__ vpT)
{
    const int tid  = threadIdx.x;
    const int proj = blockIdx.y;
    const int wv_id = tid >> 6;
    const int lane  = tid & 63;
    const int l16   = lane & 15;
    const int quad  = lane >> 4;
    const int g     = blockIdx.x * 2 + wv_id;   // 0..511 row-group
    const int m0    = g * 16;

    const float* x     = (proj == 0) ? q  : (proj == 1) ? k  : v;
    const ushort* wb   = w_bf + proj * 65536;
    const float* bias  = (proj == 0) ? bq : (proj == 1) ? bk : bvp;

    const float* arow = x + (size_t)(m0 + l16) * DM + quad * 8;

    f32x4 acc[4];
#pragma unroll
    for (int t = 0; t < 4; t++) acc[t] = (f32x4){0.f, 0.f, 0.f, 0.f};

#pragma unroll 2
    for (int kb = 0; kb < DM; kb += 32) {
        float4 f0 = *(const float4*)(arow + kb);
        float4 f1 = *(const float4*)(arow + kb + 4);
        ushort ta[8] = { f2bf(f0.x), f2bf(f0.y), f2bf(f0.z), f2bf(f0.w),
                         f2bf(f1.x), f2bf(f1.y), f2bf(f1.z), f2bf(f1.w) };
        short8 a = *(short8*)ta;
#pragma unroll
        for (int t = 0; t < 4; t++) {
            short8 b = *(const short8*)(wb + (size_t)(t * 16 + l16) * DM + kb + quad * 8);
            acc[t] = __builtin_amdgcn_mfma_f32_16x16x32_bf16(a, b, acc[t], 0, 0, 0);
        }
    }

    // C/D layout: n = t*16 + l16, row = quad*4 + r
#pragma unroll
    for (int t = 0; t < 4; t++) {
        int n = t * 16 + l16;
        float bb_ = bias[n];
#pragma unroll
        for (int r = 0; r < 4; r++) {
            int grow = m0 + quad * 4 + r;
            ushort h = f2bf(acc[t][r] + bb_);
            if (proj == 0)      qp[(size_t)grow * DN + n] = h;
            else if (proj == 1) kp[(size_t)grow * DN + n] = h;
            else {
                int bb = grow >> 11, s = grow & 2047;
                vpT[((size_t)bb * DN + n) * SS + s] = h;
            }
        }
    }
}

// ---------------------------------------------------------------------------
// flash: one block = one q-group (16 rows); 4 waves each own a 512-key
// slice (barrier-free main loop, wave-private LDS P roundtrip). In-block
// merge of the 4 (O,m,l) partials through LDS after ONE __syncthreads,
// writing the final normalized output directly.
// vs R4: eliminates the combine kernel (1 dispatch + launch gap) and ALL
// part_O/part_ml global traffic (~19 MB/iter). Main loop untouched.
// ---------------------------------------------------------------------------
__global__ __launch_bounds__(256, 4) void flash_kernel(
    const float* __restrict__ mask,
    const ushort* __restrict__ qp,
    const ushort* __restrict__ kp,
    const ushort* __restrict__ vpT,
    float* __restrict__ out)        // [8192][64] fp32, final
{
    __shared__ __align__(16) ushort p_lds[4][16][80];  // 160B row stride: quads spread 8 banks
    __shared__ __align__(16) float sO[4][16][68];      // +4 pad: quad-stride 272%32=16 -> 2-way
    __shared__ float sm[4][16];
    __shared__ float sl[4][16];

    const int tid  = threadIdx.x;
    const int wv   = tid >> 6;
    const int lane = tid & 63;
    const int l16  = lane & 15;
    const int quad = lane >> 4;

    const int qg = blockIdx.x & 127;              // q-group within batch (128/batch)
    const int b  = blockIdx.x >> 7;

    // Q fragments (A-layout), direct from global
    const ushort* qbase = qp + ((size_t)b * SS + qg * 16 + l16) * DN + quad * 8;
    short8 aq0 = *(const short8*)(qbase);
    short8 aq1 = *(const short8*)(qbase + 32);

    float m_r[4] = { -__builtin_inff(), -__builtin_inff(),
                     -__builtin_inff(), -__builtin_inff() };
    float l_r[4] = { 0.f, 0.f, 0.f, 0.f };
    f32x4 Oacc[4];
#pragma unroll
    for (int t = 0; t < 4; t++) Oacc[t] = (f32x4){0.f, 0.f, 0.f, 0.f};

    const size_t mrow0 = ((size_t)b * SS + qg * 16 + quad * 4) * SS;
    const int k_begin = wv * (SS / 4);            // wave-private 512-key slice
    const int k_end   = k_begin + (SS / 4);

    for (int k0 = k_begin; k0 < k_end; k0 += 64) {
        // fp32 mask loads (argmax decided by ~1e2 score gaps -> must stay fp32)
        float mk[4][4];
#pragma unroll
        for (int t = 0; t < 4; t++)
#pragma unroll
            for (int r = 0; r < 4; r++)
                mk[t][r] = mask[mrow0 + (size_t)r * SS + k0 + t * 16 + l16];

        // S = qp . kp^T ; B-frags direct from global kp (row-major)
        f32x4 sc[4];
#pragma unroll
        for (int t = 0; t < 4; t++) {
            const ushort* kb_ = kp + ((size_t)b * SS + k0 + t * 16 + l16) * DN + quad * 8;
            short8 bk0 = *(const short8*)(kb_);
            short8 bk1 = *(const short8*)(kb_ + 32);
            f32x4 z = (f32x4){0.f, 0.f, 0.f, 0.f};
            z = __builtin_amdgcn_mfma_f32_16x16x32_bf16(aq0, bk0, z, 0, 0, 0);
            z = __builtin_amdgcn_mfma_f32_16x16x32_bf16(aq1, bk1, z, 0, 0, 0);
            sc[t] = z;
        }

        // online softmax per accumulator reg (one q row per reg)
#pragma unroll
        for (int r = 0; r < 4; r++) {
            float s[4];
            float tmax = -__builtin_inff();
#pragma unroll
            for (int t = 0; t < 4; t++) {
                s[t] = sc[t][r] * 0.125f - 1e9f * mk[t][r];
                tmax = fmaxf(tmax, s[t]);
            }
#pragma unroll
            for (int off = 8; off >= 1; off >>= 1)
                tmax = fmaxf(tmax, __shfl_xor(tmax, off, 16));
            float mnew  = fmaxf(m_r[r], tmax);
            float alpha = __expf(m_r[r] - mnew);
            m_r[r] = mnew;
            float rs = 0.f;
#pragma unroll
            for (int t = 0; t < 4; t++) {
                float pv = __expf(s[t] - mnew);
                rs += pv;
                p_lds[wv][quad * 4 + r][t * 16 + l16] = f2bf(pv);
            }
#pragma unroll
            for (int off = 8; off >= 1; off >>= 1)
                rs += __shfl_xor(rs, off, 16);
            l_r[r] = l_r[r] * alpha + rs;
#pragma unroll
            for (int tf = 0; tf < 4; tf++)
                Oacc[tf][r] *= alpha;
        }
        // wave-private LDS roundtrip: in-order DS pipe, no barrier needed

        short8 ap0 = *(const short8*)&p_lds[wv][l16][quad * 8];
        short8 ap1 = *(const short8*)&p_lds[wv][l16][32 + quad * 8];
#pragma unroll
        for (int tf = 0; tf < 4; tf++) {
            const ushort* vb_ = vpT + ((size_t)b * DN + tf * 16 + l16) * SS + k0 + quad * 8;
            short8 bv0 = *(const short8*)(vb_);
            short8 bv1 = *(const short8*)(vb_ + 32);
            Oacc[tf] = __builtin_amdgcn_mfma_f32_16x16x32_bf16(ap0, bv0, Oacc[tf], 0, 0, 0);
            Oacc[tf] = __builtin_amdgcn_mfma_f32_16x16x32_bf16(ap1, bv1, Oacc[tf], 0, 0, 0);
        }
    }

    // park partials in LDS: row = quad*4+r, col = tf*16+l16 (C/D layout)
#pragma unroll
    for (int r = 0; r < 4; r++) {
        if (l16 == 0) {
            sm[wv][quad * 4 + r] = m_r[r];
            sl[wv][quad * 4 + r] = l_r[r];
        }
#pragma unroll
        for (int tf = 0; tf < 4; tf++)
            sO[wv][quad * 4 + r][tf * 16 + l16] = Oacc[tf][r];
    }
    __syncthreads();

    // in-block combine: 256 threads, col = tid&63, rows (tid>>6) + 4*rr
    const int col = tid & 63;
    const int rq  = tid >> 6;
#pragma unroll
    for (int rr = 0; rr < 4; rr++) {
        const int row = rq * 4 + rr;
        float m0_ = sm[0][row], m1_ = sm[1][row], m2_ = sm[2][row], m3_ = sm[3][row];
        float M = fmaxf(fmaxf(m0_, m1_), fmaxf(m2_, m3_));
        float e0 = __expf(m0_ - M), e1 = __expf(m1_ - M),
              e2 = __expf(m2_ - M), e3 = __expf(m3_ - M);
        float L = e0 * sl[0][row] + e1 * sl[1][row] + e2 * sl[2][row] + e3 * sl[3][row];
        float acc = e0 * sO[0][row][col] + e1 * sO[1][row][col]
                  + e2 * sO[2][row][col] + e3 * sO[3][row][col];
        out[((size_t)b * SS + qg * 16 + row) * DN + col] = acc / L;
    }
}

extern "C" void kernel_launch(void* const* d_in, const int* in_sizes, int n_in,
                              void* d_out, int out_size, void* d_ws, size_t ws_size,
                              hipStream_t stream) {
    const float* q    = (const float*)d_in[0];
    const float* k    = (const float*)d_in[1];
    const float* v    = (const float*)d_in[2];
    const float* mask = (const float*)d_in[3];
    const float* wq   = (const float*)d_in[4];
    const float* bq   = (const float*)d_in[5];
    const float* wk   = (const float*)d_in[6];
    const float* bk   = (const float*)d_in[7];
    const float* wv   = (const float*)d_in[8];
    const float* bv   = (const float*)d_in[9];
    float* out = (float*)d_out;

    // workspace layout (no partials needed: k-split merged in-block)
    char* p = (char*)d_ws;
    ushort* w_bf = (ushort*)p;                 p += 3 * 65536 * sizeof(ushort);   // 384 KB
    ushort* qp   = (ushort*)p;                 p += (size_t)BB * SS * DN * 2;     // 1 MB
    ushort* kp   = (ushort*)p;                 p += (size_t)BB * SS * DN * 2;     // 1 MB
    ushort* vpT  = (ushort*)p;                 p += (size_t)BB * SS * DN * 2;     // 1 MB

    prep_w<<<192, 256, 0, stream>>>(wq, wk, wv, w_bf);
    proj_kernel<<<dim3(256, 3), 128, 0, stream>>>(q, k, v, w_bf, bq, bk, bv, qp, kp, vpT);
    flash_kernel<<<BB * 128, 256, 0, stream>>>(mask, qp, kp, vpT, out);
}